// Round 5
// baseline (158.083 us; speedup 1.0000x reference)
//
#include <hip/hip_runtime.h>

typedef __attribute__((ext_vector_type(8))) short bf16x8;
typedef __attribute__((ext_vector_type(4))) float f32x4;

__device__ __forceinline__ float bf2f(unsigned short u) {
    union { unsigned u; float f; } x; x.u = (unsigned)u << 16; return x.f;
}
__device__ __forceinline__ unsigned short f2bf(float f) {
    union { float f; unsigned u; } x; x.f = f;
    unsigned r = x.u + 0x7fffu + ((x.u >> 16) & 1u);
    return (unsigned short)(r >> 16);
}

// ---------------------------------------------------------------------------
// Weight prep (verified R4): convert to bf16, fold conv into wceff, pad.
//   W1b    [256][256]  (k>=128 zero)            @ 0        (65536)
//   wceffb [4][128][256] (n>=96 rows zero)      @ 65536    (131072)
//   Wcatb  [4][256][256] (k>=96 zero)           @ 196608   (262144)
//   Wf1b   [4][256][256]                        @ 458752   (262144)
//   Wf2b   [4][256][256]                        @ 720896   (262144)
//   bceff  [4][128] f32                         @ 983040 shorts
// ---------------------------------------------------------------------------
__global__ __launch_bounds__(256) void prep(
    const float* __restrict__ filters,
    const float* __restrict__ Wc1, const float* __restrict__ Wc2, const float* __restrict__ Wc3,
    const float* __restrict__ bc1, const float* __restrict__ bc2, const float* __restrict__ bc3,
    const float* __restrict__ W1, const float* __restrict__ Wcat,
    const float* __restrict__ Wf1, const float* __restrict__ Wf2,
    unsigned short* __restrict__ W1b, unsigned short* __restrict__ wceffb,
    float* __restrict__ bceff, unsigned short* __restrict__ Wcatb,
    unsigned short* __restrict__ Wf1b, unsigned short* __restrict__ Wf2b)
{
    int idx = blockIdx.x * 256 + threadIdx.x;
    if (idx < 65536) {
        int n = idx >> 8, k = idx & 255;
        W1b[idx] = (k < 128) ? f2bf(W1[n * 128 + k]) : (unsigned short)0;
    } else if (idx < 196608) {
        int j = idx - 65536;
        int i = j >> 15, n = (j >> 8) & 127, h = j & 255;
        if (n < 96) {
            int c = n >> 5, jj = n & 31;
            const float* Wc = (c == 0) ? Wc1 : (c == 1) ? Wc2 : Wc3;
            const float* f  = filters + c * 25;
            float acc = 0.f;
            #pragma unroll
            for (int k = 0; k < 25; ++k) {
                int hh = h + 12 - k;
                if (hh >= 0 && hh < 256) acc += f[k] * Wc[(i * 32 + jj) * 256 + hh];
            }
            wceffb[j] = f2bf(acc);
            if (h == 0) {
                const float* bc = (c == 0) ? bc1 : (c == 1) ? bc2 : bc3;
                bceff[i * 128 + n] = bc[i * 32 + jj];
            }
        } else {
            wceffb[j] = 0;
            if (h == 0) bceff[i * 128 + n] = 0.f;
        }
    } else if (idx < 458752) {
        int j = idx - 196608;
        int i = j >> 16, rem = j & 65535, n = rem >> 8, k = rem & 255;
        Wcatb[j] = (k < 96) ? f2bf(Wcat[(i * 256 + n) * 96 + k]) : (unsigned short)0;
    } else if (idx < 720896) {
        int j = idx - 458752;
        Wf1b[j] = f2bf(Wf1[j]);
    } else if (idx < 983040) {
        int j = idx - 720896;
        Wf2b[j] = f2bf(Wf2[j]);
    }
}

// ---------------------------------------------------------------------------
// One GEMM stage. acc = mfma(A=W_frag, B=act_frag): D col(lane&15)=batch row,
// D row((lane>>4)*4+reg)=out channel. act LDS = 1KB frag tiles, slot=lane*16B.
// W streams GLOBAL -> VGPR (per-wave, 2-deep ping-pong). NO K-loop barriers.
// ---------------------------------------------------------------------------
template<int NKC, int NWT>
__device__ __forceinline__ void gemm_stage(
    const unsigned short* __restrict__ Wg,   // [NT*16][256] padded rows
    const float* __restrict__ bias,
    const unsigned short* actIn, unsigned short* actOut,
    float* scratch,                          // >= 1536 floats dedicated LDS
    int actmode, const float* alphap,
    const unsigned short* resbuf,
    const float* g, const float* be,
    int finaldot, const float* Wout, const float* boutp, float* outg, int rowbase)
{
    const int tid  = threadIdx.x;
    const int lane = tid & 63;
    const int wave = tid >> 6;
    const int wm   = wave >> 2;              // 0..1  (64 rows each)
    const int wn   = wave & 3;               // 0..3  (NWT*16 cols each)
    const int l15  = lane & 15;
    const int hi   = lane >> 4;

    f32x4 acc[4][NWT];
    #pragma unroll
    for (int mt = 0; mt < 4; ++mt)
        #pragma unroll
        for (int nt = 0; nt < NWT; ++nt) acc[mt][nt] = (f32x4){0.f, 0.f, 0.f, 0.f};

    // per-wave W base: row = (wn*NWT+nt)*16 + l15, k-slot hi*8
    const unsigned short* wbase = Wg + ((size_t)(wn * NWT) * 16 + l15) * 256 + hi * 8;
    const unsigned short* abase = actIn + (wm * 4) * 8 * 512 + lane * 8;

    bf16x8 w0[NWT], w1[NWT], a0[4], a1[4];

    #define LOADW(dst, kc) { _Pragma("unroll") \
        for (int nt = 0; nt < NWT; ++nt) \
            dst[nt] = *(const bf16x8*)(wbase + nt * 16 * 256 + (kc) * 32); }
    #define LOADA(dst, kc) { _Pragma("unroll") \
        for (int mt = 0; mt < 4; ++mt) \
            dst[mt] = *(const bf16x8*)(abase + (mt * 8 + (kc)) * 512); }
    #define FMAS(areg, wreg) { \
        __builtin_amdgcn_s_setprio(1); \
        _Pragma("unroll") \
        for (int mt = 0; mt < 4; ++mt) { _Pragma("unroll") \
            for (int nt = 0; nt < NWT; ++nt) \
                acc[mt][nt] = __builtin_amdgcn_mfma_f32_16x16x32_bf16( \
                    wreg[nt], areg[mt], acc[mt][nt], 0, 0, 0); } \
        __builtin_amdgcn_s_setprio(0); }

    LOADW(w0, 0); LOADA(a0, 0);
    #pragma unroll
    for (int kc = 0; kc < NKC; kc += 2) {
        if (kc + 1 < NKC) { LOADW(w1, kc + 1); LOADA(a1, kc + 1); }
        FMAS(a0, w0);
        if (kc + 2 < NKC) { LOADW(w0, kc + 2); LOADA(a0, kc + 2); }
        if (kc + 1 < NKC) FMAS(a1, w1);
    }
    #undef LOADW
    #undef LOADA
    #undef FMAS

    // ---- epilogue: bias -> act -> res -> (LN) -> store/dot  (verified R4) ----
    const float alpha = alphap ? alphap[0] : 0.1f;
    float vv[4][NWT][4];
    #pragma unroll
    for (int mt = 0; mt < 4; ++mt) {
        #pragma unroll
        for (int nt = 0; nt < NWT; ++nt) {
            const int nb = wn * (NWT * 16) + nt * 16 + hi * 4;
            const float4 bs = *(const float4*)(bias + nb);
            float t0 = acc[mt][nt][0] + bs.x;
            float t1 = acc[mt][nt][1] + bs.y;
            float t2 = acc[mt][nt][2] + bs.z;
            float t3 = acc[mt][nt][3] + bs.w;
            if (actmode) {
                t0 = t0 >= 0.f ? t0 : alpha * t0;
                t1 = t1 >= 0.f ? t1 : alpha * t1;
                t2 = t2 >= 0.f ? t2 : alpha * t2;
                t3 = t3 >= 0.f ? t3 : alpha * t3;
            }
            if (resbuf) {
                const int ro = ((wm * 4 + mt) * 8 + (nb >> 5)) * 512
                             + (l15 + ((nb >> 3) & 3) * 16) * 8 + (nb & 7);
                const ushort4 rv = *(const ushort4*)(resbuf + ro);
                t0 += bf2f(rv.x); t1 += bf2f(rv.y); t2 += bf2f(rv.z); t3 += bf2f(rv.w);
            }
            vv[mt][nt][0] = t0; vv[mt][nt][1] = t1;
            vv[mt][nt][2] = t2; vv[mt][nt][3] = t3;
        }
    }

    float* lnred = scratch;                  // 1024 floats
    float mean[4], rstd[4];
    if (g) {
        #pragma unroll
        for (int mt = 0; mt < 4; ++mt) {
            float s = 0.f, q = 0.f;
            #pragma unroll
            for (int nt = 0; nt < NWT; ++nt)
                #pragma unroll
                for (int r = 0; r < 4; ++r) { const float v = vv[mt][nt][r]; s += v; q += v * v; }
            s += __shfl_xor(s, 16); s += __shfl_xor(s, 32);
            q += __shfl_xor(q, 16); q += __shfl_xor(q, 32);
            if (hi == 0)
                *(float2*)(lnred + (wm * 64 + mt * 16 + l15) * 8 + wn * 2) = make_float2(s, q);
        }
        __syncthreads();
        #pragma unroll
        for (int mt = 0; mt < 4; ++mt) {
            const int m = wm * 64 + mt * 16 + l15;
            const float4 p0 = *(const float4*)(lnred + m * 8);
            const float4 p1 = *(const float4*)(lnred + m * 8 + 4);
            const float s = p0.x + p0.z + p1.x + p1.z;
            const float q = p0.y + p0.w + p1.y + p1.w;
            const float mu = s * (1.f / 256.f);
            mean[mt] = mu;
            rstd[mt] = rsqrtf(q * (1.f / 256.f) - mu * mu + 1e-5f);
        }
    }

    float* dotp = scratch + 1024;            // 512 floats
    #pragma unroll
    for (int mt = 0; mt < 4; ++mt) {
        float dp = 0.f;
        #pragma unroll
        for (int nt = 0; nt < NWT; ++nt) {
            const int nb = wn * (NWT * 16) + nt * 16 + hi * 4;
            float o0 = vv[mt][nt][0], o1 = vv[mt][nt][1], o2 = vv[mt][nt][2], o3 = vv[mt][nt][3];
            if (g) {
                const float4 gv = *(const float4*)(g + nb);
                const float4 bv = *(const float4*)(be + nb);
                o0 = (o0 - mean[mt]) * rstd[mt] * gv.x + bv.x;
                o1 = (o1 - mean[mt]) * rstd[mt] * gv.y + bv.y;
                o2 = (o2 - mean[mt]) * rstd[mt] * gv.z + bv.z;
                o3 = (o3 - mean[mt]) * rstd[mt] * gv.w + bv.w;
            }
            if (!finaldot) {
                const ushort4 ov = {f2bf(o0), f2bf(o1), f2bf(o2), f2bf(o3)};
                *(ushort4*)(actOut + ((wm * 4 + mt) * 8 + (nb >> 5)) * 512
                            + (l15 + ((nb >> 3) & 3) * 16) * 8 + (nb & 7)) = ov;
            } else {
                const float4 wv = *(const float4*)(Wout + nb);
                dp += o0 * wv.x + o1 * wv.y + o2 * wv.z + o3 * wv.w;
            }
        }
        if (finaldot) {
            dp += __shfl_xor(dp, 16); dp += __shfl_xor(dp, 32);
            if (hi == 0) dotp[(wm * 64 + mt * 16 + l15) * 4 + wn] = dp;
        }
    }
    if (finaldot) {
        __syncthreads();
        if (tid < 128) {
            const float4 pp = *(const float4*)(dotp + tid * 4);
            outg[rowbase + tid] = pp.x + pp.y + pp.z + pp.w + boutp[0];
        }
    }
    __syncthreads();   // stage-end barrier (actOut visible; actIn reads done)
}

// ---------------------------------------------------------------------------
// Persistent mega-kernel: 256 blocks x 512 threads, 128 rows per block.
// LDS = actA 64KB + actB 64KB + scratch 6KB = 134KB.
// ---------------------------------------------------------------------------
__global__ __launch_bounds__(512, 2) void mega(
    const float* __restrict__ x,
    const unsigned short* __restrict__ W1b, const float* __restrict__ b1,
    const float* __restrict__ a0, const float* __restrict__ g0, const float* __restrict__ be0,
    const unsigned short* __restrict__ wceffb, const float* __restrict__ bceff,
    const unsigned short* __restrict__ Wcatb, const float* __restrict__ bcat,
    const float* __restrict__ g1, const float* __restrict__ be1,
    const unsigned short* __restrict__ Wf1b, const float* __restrict__ bf1,
    const float* __restrict__ af,
    const unsigned short* __restrict__ Wf2b, const float* __restrict__ bf2,
    const float* __restrict__ g2, const float* __restrict__ be2,
    const float* __restrict__ Wout, const float* __restrict__ boutp,
    float* __restrict__ outg)
{
    __shared__ __align__(16) unsigned short actA[32768];   // 64KB
    __shared__ __align__(16) unsigned short actB[32768];   // 64KB
    __shared__ __align__(16) float scratch[1536];          // 6KB (LN + dot)

    const int tid = threadIdx.x;
    const int rowbase = blockIdx.x * 128;

    // phase 0: stage x (f32) -> actB fragment tiles (bf16), K=128
    {
        const int r = tid >> 2, q = tid & 3;
        const float* xp = x + (size_t)(rowbase + r) * 128 + q * 32;
        #pragma unroll
        for (int gi = 0; gi < 8; ++gi) {
            const float4 xv = *(const float4*)(xp + gi * 4);
            const int j = q * 32 + gi * 4;
            const ushort4 o = {f2bf(xv.x), f2bf(xv.y), f2bf(xv.z), f2bf(xv.w)};
            *(ushort4*)(actB + ((r >> 4) * 8 + (j >> 5)) * 512
                        + ((r & 15) + ((j >> 3) & 3) * 16) * 8 + (j & 7)) = o;
        }
        __syncthreads();
    }

    // out = ln(prelu(x @ W1^T + b1, a0), g0, be0)        B -> A
    gemm_stage<4, 4>(W1b, b1, actB, actA, scratch, 1, a0, nullptr, g0, be0,
                     0, nullptr, nullptr, nullptr, 0);

    for (int it = 0; it < 4; ++it) {
        // xcat = lrelu(out @ wceff^T + bceff, 0.1)       A -> B  (N=128)
        gemm_stage<8, 2>(wceffb + it * 32768, bceff + it * 128, actA, actB, scratch,
                         2, nullptr, nullptr, nullptr, nullptr,
                         0, nullptr, nullptr, nullptr, 0);
        // out = ln(xcat @ Wcat^T + bcat + out)           B -> A (res A, in-place safe)
        gemm_stage<4, 4>(Wcatb + it * 65536, bcat + it * 256, actB, actA, scratch,
                         0, nullptr, actA, g1 + it * 256, be1 + it * 256,
                         0, nullptr, nullptr, nullptr, 0);
        // h = prelu(out @ Wf1^T + bf1, af[it])           A -> B
        gemm_stage<8, 4>(Wf1b + it * 65536, bf1 + it * 256, actA, actB, scratch,
                         1, af + it, nullptr, nullptr, nullptr,
                         0, nullptr, nullptr, nullptr, 0);
        // out = ln(h @ Wf2^T + bf2 + out); last iter fuses final matvec
        gemm_stage<8, 4>(Wf2b + it * 65536, bf2 + it * 256, actB, actA, scratch,
                         0, nullptr, actA, g2 + it * 256, be2 + it * 256,
                         (it == 3) ? 1 : 0, Wout, boutp, outg, rowbase);
    }
}

extern "C" void kernel_launch(void* const* d_in, const int* in_sizes, int n_in,
                              void* d_out, int out_size, void* d_ws, size_t ws_size,
                              hipStream_t stream)
{
    const float* x       = (const float*)d_in[0];
    const float* filters = (const float*)d_in[1];
    const float* W1      = (const float*)d_in[2];
    const float* b1      = (const float*)d_in[3];
    const float* a0      = (const float*)d_in[4];
    const float* g0      = (const float*)d_in[5];
    const float* be0     = (const float*)d_in[6];
    const float* Wc1     = (const float*)d_in[7];
    const float* bc1     = (const float*)d_in[8];
    const float* Wc2     = (const float*)d_in[9];
    const float* bc2     = (const float*)d_in[10];
    const float* Wc3     = (const float*)d_in[11];
    const float* bc3     = (const float*)d_in[12];
    const float* Wcat    = (const float*)d_in[13];
    const float* bcat    = (const float*)d_in[14];
    const float* g1      = (const float*)d_in[15];
    const float* be1     = (const float*)d_in[16];
    const float* Wf1     = (const float*)d_in[17];
    const float* bf1     = (const float*)d_in[18];
    const float* af      = (const float*)d_in[19];
    const float* Wf2     = (const float*)d_in[20];
    const float* bf2     = (const float*)d_in[21];
    const float* g2      = (const float*)d_in[22];
    const float* be2     = (const float*)d_in[23];
    const float* Wout    = (const float*)d_in[24];
    const float* boutp   = (const float*)d_in[25];
    float* outf = (float*)d_out;

    unsigned short* p = (unsigned short*)d_ws;
    unsigned short* W1b    = p;              // 65536
    unsigned short* wceffb = p + 65536;      // 131072
    unsigned short* Wcatb  = p + 196608;     // 262144
    unsigned short* Wf1b   = p + 458752;     // 262144
    unsigned short* Wf2b   = p + 720896;     // 262144
    float*          bceff  = (float*)(p + 983040);  // 512 floats

    prep<<<dim3(3840), dim3(256), 0, stream>>>(
        filters, Wc1, Wc2, Wc3, bc1, bc2, bc3, W1, Wcat, Wf1, Wf2,
        W1b, wceffb, bceff, Wcatb, Wf1b, Wf2b);

    mega<<<dim3(256), dim3(512), 0, stream>>>(
        x, W1b, b1, a0, g0, be0, wceffb, bceff, Wcatb, bcat, g1, be1,
        Wf1b, bf1, af, Wf2b, bf2, g2, be2, Wout, boutp, outf);
}